// Round 1
// baseline (13904.138 us; speedup 1.0000x reference)
//
#include <hip/hip_runtime.h>

#define TT 256
#define BDIM 256
#define MT 32

typedef unsigned short u16;
typedef unsigned int u32;
typedef __attribute__((ext_vector_type(8))) short bf16x8;
typedef __attribute__((ext_vector_type(4))) float f32x4;

// async global->LDS, 16B/lane; LDS dest is wave-uniform base + lane*16
#define GLL(g, l) __builtin_amdgcn_global_load_lds( \
    (const __attribute__((address_space(1))) void*)(g), \
    (__attribute__((address_space(3))) void*)(l), 16, 0, 0)

struct P {
  const float* obs; const float* action; const int* is_first;
  const float* w_prior_in; const float* g_prior_in; const float* bb_prior_in;
  const float* w_gru; const float* g_gru; const float* bb_gru;
  const float* w_prior_out; const float* g_prior_out; const float* bb_prior_out;
  const float* w_prior_stats; const float* b_prior_stats;
  const float* w_post; const float* g_post; const float* bb_post;
  const float* w_post_stats; const float* b_post_stats;
  const float* initial_deter;
  float* out;
  // weights: blocked per 32-k chunk [kc][N][32] u16, XOR-swizzled rows
  u16 *WgT3;    // 96 kc x 1536 n   K-order [deter3(1536) | h3(1536)], planes W:[hi|hi|lo]
  u16 *W2T3;    // 51 kc x 1024 n   K-order [deter3(1536) | obs3(96)]
  u16 *WsT3;    // 96 kc x 128 n    K-order h2 planes
  float *deter0, *init_mean;
  int *segb, *segt0, *nact, *qhead;
  // per-block slots
  u16 *arow;    // [NB][100][1024] u16 swizzled chunks: d3 ch0-47, h3 ch48-95, obs3 ch96-98
  u16 *h2;      // [NB][96][1024]
  float *gates; // [NB][32][1536]
  float *hraw;  // [NB][32][1024]
  float *deter; // [NB][32][512]
  float *stoch; // [NB][32][32]
  int NB;
};

__device__ __forceinline__ float b2f(u16 u) {
  union { float f; u32 i; } v; v.i = ((u32)u) << 16; return v.f;
}
__device__ __forceinline__ u16 f2b(float f) {
  union { float f; u32 i; } v; v.f = f;
  u32 r = v.i + 0x7FFF + ((v.i >> 16) & 1);   // RNE
  return (u16)(r >> 16);
}
__device__ __forceinline__ float sigm(float x) { return 1.f / (1.f + __expf(-x)); }
__device__ __forceinline__ float splus(float x) { return x > 15.f ? x : log1pf(__expf(x)); }

// write one u16 at logical (row, kk) into a swizzled chunked buffer
__device__ __forceinline__ void awr(u16* base, int row, int kk, u16 v) {
  base[((kk >> 5) << 10) + (((row << 5) + (kk & 31)) ^ ((row & 7) << 3))] = v;
}

// ---- prior_in head: h = silu(ln(x @ Wpi)); writes h3 planes (cols 1536..3071) ----
__device__ __forceinline__ void h_from_x(const P& p, u16* slotA, int i, float xv, int lane) {
  float a0[8];
  #pragma unroll
  for (int c = 0; c < 8; ++c) a0[c] = 0.f;
  #pragma unroll 4
  for (int j = 0; j < 36; ++j) {
    float s = __shfl(xv, j, 64);
    const float* wr = p.w_prior_in + j * 512 + lane;
    #pragma unroll
    for (int c = 0; c < 8; ++c) a0[c] = fmaf(s, wr[c << 6], a0[c]);
  }
  float sm = 0.f, sq = 0.f;
  #pragma unroll
  for (int c = 0; c < 8; ++c) { sm += a0[c]; sq += a0[c] * a0[c]; }
  #pragma unroll
  for (int o = 32; o; o >>= 1) { sm += __shfl_xor(sm, o); sq += __shfl_xor(sq, o); }
  float m = sm * (1.f / 512.f);
  float rs = rsqrtf(sq * (1.f / 512.f) - m * m + 1e-3f);
  #pragma unroll
  for (int c = 0; c < 8; ++c) {
    int col = lane + (c << 6);
    float v = (a0[c] - m) * rs * p.g_prior_in[col] + p.bb_prior_in[col];
    v = v * sigm(v);
    u16 hi = f2b(v); u16 lo = f2b(v - b2f(hi));
    awr(slotA, i, 1536 + col, hi);
    awr(slotA, i, 2048 + col, lo);
    awr(slotA, i, 2560 + col, hi);
  }
}

// ================= prep kernels =================
__global__ void k_weights(P p) {
  const int E1 = 1536 * 3072, E2 = 1024 * 1632, E3 = 128 * 3072;
  const int total = E1 + E2 + E3;
  for (int idx = blockIdx.x * blockDim.x + threadIdx.x; idx < total;
       idx += gridDim.x * blockDim.x) {
    float w; u16* base; size_t dstIdx; int lo_sel;
    if (idx < E1) {                       // Wg: n in [0,1536), kk in [0,3072)
      int n = idx / 3072, kk = idx - n * 3072;
      int sub = (kk < 1536) ? kk : kk - 1536;
      int c = sub & 511, pl = sub >> 9;
      w = (kk < 1536) ? p.w_gru[(512 + c) * 1536 + n]   // deter rows
                      : p.w_gru[c * 1536 + n];          // h rows
      lo_sel = (pl == 2);
      base = p.WgT3;
      dstIdx = (size_t)(kk >> 5) * 49152 + (((n << 5) + (kk & 31)) ^ ((n & 7) << 3));
    } else if (idx < E1 + E2) {           // W2: n in [0,1024), kk in [0,1632)
      int t = idx - E1;
      int n = t / 1632, kk = t - n * 1632;
      if (kk < 1536) {
        int c = kk & 511, pl = kk >> 9;
        w = (n < 512) ? p.w_prior_out[c * 512 + n] : p.w_post[c * 512 + (n - 512)];
        lo_sel = (pl == 2);
      } else {
        int j = kk - 1536; int c = j & 31, pl = j >> 5;
        w = (n >= 512 && c < 18) ? p.w_post[(512 + c) * 512 + (n - 512)] : 0.f;
        lo_sel = (pl == 2);
      }
      base = p.W2T3;
      dstIdx = (size_t)(kk >> 5) * 32768 + (((n << 5) + (kk & 31)) ^ ((n & 7) << 3));
    } else {                              // Ws: n in [0,128), kk in [0,3072)
      int t = idx - E1 - E2;
      int n = t / 3072, kk = t - n * 3072;
      int c = kk & 1023, pl = kk >> 10;
      if (n < 64) w = (c < 512) ? p.w_prior_stats[c * 64 + n] : 0.f;
      else        w = (c >= 512) ? p.w_post_stats[(c - 512) * 64 + (n - 64)] : 0.f;
      lo_sel = (pl == 2);
      base = p.WsT3;
      dstIdx = (size_t)(kk >> 5) * 4096 + (((n << 5) + (kk & 31)) ^ ((n & 7) << 3));
    }
    u16 hi = f2b(w); u16 lo = f2b(w - b2f(hi));
    base[dstIdx] = lo_sel ? lo : hi;
  }
}

__global__ void k_init_state(P p) {
  __shared__ float d0s[512], tmp[512], red[256];
  int tid = threadIdx.x;
  for (int n = tid; n < 512; n += 256) { d0s[n] = tanhf(p.initial_deter[n]); p.deter0[n] = d0s[n]; }
  __syncthreads();
  for (int n = tid; n < 512; n += 256) {
    float s = 0.f;
    for (int d = 0; d < 512; ++d) s = fmaf(d0s[d], p.w_prior_out[d * 512 + n], s);
    tmp[n] = s;
  }
  __syncthreads();
  float ls = 0.f, lq = 0.f;
  for (int n = tid; n < 512; n += 256) { ls += tmp[n]; lq += tmp[n] * tmp[n]; }
  red[tid] = ls; __syncthreads();
  for (int s = 128; s; s >>= 1) { if (tid < s) red[tid] += red[tid + s]; __syncthreads(); }
  float m = red[0] * (1.f / 512.f); __syncthreads();
  red[tid] = lq; __syncthreads();
  for (int s = 128; s; s >>= 1) { if (tid < s) red[tid] += red[tid + s]; __syncthreads(); }
  float rs = rsqrtf(red[0] * (1.f / 512.f) - m * m + 1e-3f); __syncthreads();
  for (int n = tid; n < 512; n += 256) {
    float h = (tmp[n] - m) * rs * p.g_prior_out[n] + p.bb_prior_out[n];
    tmp[n] = h * sigm(h);
  }
  __syncthreads();
  if (tid < 32) {
    float s = 0.f;
    for (int d = 0; d < 512; ++d) s = fmaf(tmp[d], p.w_prior_stats[d * 64 + tid], s);
    p.init_mean[tid] = s + p.b_prior_stats[tid];
  }
}

__global__ void k_segments(P p) {
  __shared__ int hist[257], off[258], cur[257];
  int tid = threadIdx.x;
  if (tid == 0) *p.qhead = 0;
  for (int i = tid; i < 257; i += 256) hist[i] = 0;
  __syncthreads();
  int b = tid;
  { int t = 0;
    while (t < TT) {
      int t0 = t; t++;
      while (t < TT && p.is_first[b * TT + t] == 0) t++;
      atomicAdd(&hist[t - t0], 1);
    } }
  __syncthreads();
  if (tid == 0) {
    int run = 0;
    for (int len = 256; len >= 0; --len) { off[len] = run; run += hist[len]; }
  }
  __syncthreads();
  for (int i = tid; i < 257; i += 256) { cur[i] = off[i]; p.nact[i] = off[i]; }
  __syncthreads();
  { int t = 0;
    while (t < TT) {
      int t0 = t; t++;
      while (t < TT && p.is_first[b * TT + t] == 0) t++;
      int idx = atomicAdd(&cur[t - t0], 1);
      p.segb[idx] = b; p.segt0[idx] = t0;
    } }
}

// ---- block-local GEMM pass: C(32 x 256) += A(32 x NSTEPS*32) * W^T, 3-deep pipeline ----
// NI=4: wave tile 32x64 (acc[2][4]); NI=2: wave tile 32x32 (acc[2][2], N=128)
template<int NI, int NSTEPS, int JAT, int JD>
__device__ __forceinline__ void gemm_pass(
    const u16* __restrict__ aBase, const u16* __restrict__ wBase,
    int wStride, int n0, u16* ldsA, u16* ldsW,
    int wave, int lane, int quad, int l15, f32x4 (&acc)[2][NI]) {

  auto stage = [&](int st, int buf) {
    int ach = (JAT < NSTEPS && st >= JAT) ? st + JD : st;
    const u16* aSrc = aBase + ((size_t)ach << 10) + (wave << 9) + (lane << 3);
    const u16* wSrc = wBase + (size_t)st * wStride + n0 * 32 + (lane << 3);
    if (wave < 2) GLL(aSrc, ldsA + buf * 1024 + (wave << 9));
    #pragma unroll
    for (int gg = 0; gg < NI; ++gg) {
      int g = wave * NI + gg;
      GLL(wSrc + (g << 9), ldsW + buf * 8192 + (g << 9));
    }
  };
  auto compute = [&](int buf) {
    const u16* A = ldsA + buf * 1024;
    const u16* W = ldsW + buf * 8192;
    int xr = (l15 & 7) << 3;
    bf16x8 af[2];
    #pragma unroll
    for (int mi = 0; mi < 2; ++mi) {
      int r = mi * 16 + l15;
      af[mi] = *(const bf16x8*)&A[((r << 5) + (quad << 3)) ^ xr];
    }
    #pragma unroll
    for (int ni = 0; ni < NI; ++ni) {
      int rr = wave * (NI * 16) + ni * 16 + l15;
      bf16x8 bv = *(const bf16x8*)&W[((rr << 5) + (quad << 3)) ^ xr];
      #pragma unroll
      for (int mi = 0; mi < 2; ++mi)
        acc[mi][ni] = __builtin_amdgcn_mfma_f32_16x16x32_bf16(af[mi], bv, acc[mi][ni], 0, 0, 0);
    }
  };

  stage(0, 0); stage(1, 1);
  int b3 = 0;
  for (int st = 0; st < NSTEPS - 1; ++st) {
    if (wave < 2) asm volatile("s_waitcnt vmcnt(%0)" :: "i"(NI + 1) : "memory");
    else          asm volatile("s_waitcnt vmcnt(%0)" :: "i"(NI) : "memory");
    __builtin_amdgcn_s_barrier();
    __builtin_amdgcn_sched_barrier(0);
    if (st + 2 < NSTEPS) {
      int bs = b3 + 2; if (bs >= 3) bs -= 3;
      stage(st + 2, bs);
    }
    compute(b3);
    ++b3; if (b3 == 3) b3 = 0;
  }
  asm volatile("s_waitcnt vmcnt(0)" ::: "memory");
  __builtin_amdgcn_s_barrier();
  __builtin_amdgcn_sched_barrier(0);
  compute(b3);
}

// ================= main persistent kernel: per-block tile queue =================
__global__ void __launch_bounds__(BDIM) k_main(P p) {
  __shared__ u16 lds[27648];   // A: 3x1024 u16 (6KB), W: 3x8192 u16 (48KB)
  __shared__ int sg;
  const int tid = threadIdx.x;
  const int wave = tid >> 6, lane = tid & 63, quad = lane >> 4, l15 = lane & 15;
  u16* ldsA = lds;
  u16* ldsW = lds + 3072;
  const int blk = blockIdx.x;
  u16* slotA = p.arow + (size_t)blk * 102400;
  u16* slotH = p.h2 + (size_t)blk * 98304;
  float* slotG = p.gates + (size_t)blk * 49152;
  float* slotR = p.hraw + (size_t)blk * 32768;
  float* slotD = p.deter + (size_t)blk * 16384;
  float* slotS = p.stoch + (size_t)blk * 1024;
  const int S_total = p.nact[0];
  const int ntiles = (S_total + MT - 1) >> 5;

  for (;;) {
    __syncthreads();
    if (tid == 0) sg = atomicAdd(p.qhead, 1);
    __syncthreads();
    int g = sg;
    if (g >= ntiles) return;
    int row0 = g * MT;
    int nr0 = S_total - row0; if (nr0 > MT) nr0 = MT;

    for (int k = 0;; ++k) {
      int Mk = p.nact[k] - row0; if (Mk > nr0) Mk = nr0;
      if (Mk <= 0) break;

      // ---- A: state init (k==0) + prior_in head ----
      for (int i = wave; i < Mk; i += 4) {
        int gi = row0 + i;
        int b = p.segb[gi], t0 = p.segt0[gi];
        float xv = 0.f;
        if (k == 0) {
          #pragma unroll
          for (int c = 0; c < 8; ++c) {
            int d = lane + (c << 6);
            float v = p.deter0[d];
            slotD[i * 512 + d] = v;
            u16 hi = f2b(v); u16 lo = f2b(v - b2f(hi));
            awr(slotA, i, d, hi);
            awr(slotA, i, 512 + d, lo);
            awr(slotA, i, 1024 + d, hi);
          }
          int ff = p.is_first[b * TT + t0];
          if (lane < 32) xv = p.init_mean[lane];
          else if (lane < 36) xv = (ff > 0) ? 0.f : p.action[((size_t)b * TT + t0) * 4 + (lane - 32)];
        } else {
          if (lane < 32) xv = slotS[i * 32 + lane];
          else if (lane < 36) xv = p.action[((size_t)b * TT + t0 + k) * 4 + (lane - 32)];
        }
        h_from_x(p, slotA, i, xv, lane);
      }
      __syncthreads();

      // ---- B: gates = arow[d3|h3] @ WgT3   (32 x 1536, K3=3072) ----
      for (int np = 0; np < 6; ++np) {
        f32x4 acc[2][4];
        #pragma unroll
        for (int a = 0; a < 2; ++a)
          #pragma unroll
          for (int bq = 0; bq < 4; ++bq) acc[a][bq] = f32x4{0.f, 0.f, 0.f, 0.f};
        gemm_pass<4, 96, 1000, 0>(slotA, p.WgT3, 49152, np * 256,
                                  ldsA, ldsW, wave, lane, quad, l15, acc);
        #pragma unroll
        for (int mi = 0; mi < 2; ++mi)
          #pragma unroll
          for (int ni = 0; ni < 4; ++ni)
            #pragma unroll
            for (int r = 0; r < 4; ++r)
              slotG[(mi * 16 + quad * 4 + r) * 1536 + np * 256 + wave * 64 + ni * 16 + l15]
                  = acc[mi][ni][r];
      }
      __syncthreads();

      // ---- C: LN(gates) -> GRU -> deter', d3/obs3 refresh, out-deter ----
      for (int i = wave; i < Mk; i += 4) {
        const float* grow = slotG + i * 1536;
        float g24[24];
        float sm = 0.f, sq = 0.f;
        #pragma unroll
        for (int c = 0; c < 24; ++c) {
          g24[c] = grow[lane + (c << 6)];
          sm += g24[c]; sq += g24[c] * g24[c];
        }
        #pragma unroll
        for (int o = 32; o; o >>= 1) { sm += __shfl_xor(sm, o); sq += __shfl_xor(sq, o); }
        float m = sm * (1.f / 1536.f);
        float rs = rsqrtf(sq * (1.f / 1536.f) - m * m + 1e-3f);
        int gi = row0 + i;
        int b = p.segb[gi], t = p.segt0[gi] + k;
        float* orow = p.out + ((size_t)b * TT + t) * 1216;
        #pragma unroll
        for (int c = 0; c < 8; ++c) {
          int d = lane + (c << 6);
          float gr = (g24[c] - m) * rs * p.g_gru[d] + p.bb_gru[d];
          float gc = (g24[c + 8] - m) * rs * p.g_gru[512 + d] + p.bb_gru[512 + d];
          float gu = (g24[c + 16] - m) * rs * p.g_gru[1024 + d] + p.bb_gru[1024 + d];
          float r_ = sigm(gr);
          float u_ = sigm(gu - 1.0f);
          float rc = r_ * gc;
          float cand = rc * sigm(rc);
          float dp = slotD[i * 512 + d];
          float dn = u_ * cand + (1.f - u_) * dp;
          slotD[i * 512 + d] = dn;
          orow[d] = dn; orow[608 + d] = dn;
          u16 hi = f2b(dn); u16 lo = f2b(dn - b2f(hi));
          awr(slotA, i, d, hi);
          awr(slotA, i, 512 + d, lo);
          awr(slotA, i, 1024 + d, hi);
        }
        if (lane < 32) {
          float ov = (lane < 18) ? p.obs[((size_t)b * TT + t) * 18 + lane] : 0.f;
          u16 hi = f2b(ov); u16 lo = f2b(ov - b2f(hi));
          awr(slotA, i, 3072 + lane, hi);
          awr(slotA, i, 3104 + lane, lo);
          awr(slotA, i, 3136 + lane, hi);
        }
      }
      __syncthreads();

      // ---- D: hraw = arow[d3|obs3] @ W2T3   (32 x 1024, K3=1632) ----
      for (int np = 0; np < 4; ++np) {
        f32x4 acc[2][4];
        #pragma unroll
        for (int a = 0; a < 2; ++a)
          #pragma unroll
          for (int bq = 0; bq < 4; ++bq) acc[a][bq] = f32x4{0.f, 0.f, 0.f, 0.f};
        gemm_pass<4, 51, 48, 48>(slotA, p.W2T3, 32768, np * 256,
                                 ldsA, ldsW, wave, lane, quad, l15, acc);
        #pragma unroll
        for (int mi = 0; mi < 2; ++mi)
          #pragma unroll
          for (int ni = 0; ni < 4; ++ni)
            #pragma unroll
            for (int r = 0; r < 4; ++r)
              slotR[(mi * 16 + quad * 4 + r) * 1024 + np * 256 + wave * 64 + ni * 16 + l15]
                  = acc[mi][ni][r];
      }
      __syncthreads();

      // ---- E: two LNs + silu -> h2 planes ----
      for (int i = wave; i < Mk; i += 4) {
        #pragma unroll
        for (int hh = 0; hh < 2; ++hh) {
          const float* hb = slotR + i * 1024 + (hh << 9);
          const float* gv = hh ? p.g_post : p.g_prior_out;
          const float* bv = hh ? p.bb_post : p.bb_prior_out;
          float v[8];
          float sm = 0.f, sq = 0.f;
          #pragma unroll
          for (int c = 0; c < 8; ++c) {
            v[c] = hb[lane + (c << 6)];
            sm += v[c]; sq += v[c] * v[c];
          }
          #pragma unroll
          for (int o = 32; o; o >>= 1) { sm += __shfl_xor(sm, o); sq += __shfl_xor(sq, o); }
          float m = sm * (1.f / 512.f);
          float rs = rsqrtf(sq * (1.f / 512.f) - m * m + 1e-3f);
          #pragma unroll
          for (int c = 0; c < 8; ++c) {
            int d = lane + (c << 6);
            float x = (v[c] - m) * rs * gv[d] + bv[d];
            x = x * sigm(x);
            int col = (hh << 9) + d;
            u16 hi = f2b(x); u16 lo = f2b(x - b2f(hi));
            awr(slotH, i, col, hi);
            awr(slotH, i, 1024 + col, lo);
            awr(slotH, i, 2048 + col, hi);
          }
        }
      }
      __syncthreads();

      // ---- F: stats = h2 @ WsT3 (32 x 128, K3=3072) + epilogue ----
      {
        f32x4 acc[2][2];
        #pragma unroll
        for (int a = 0; a < 2; ++a)
          #pragma unroll
          for (int bq = 0; bq < 2; ++bq) acc[a][bq] = f32x4{0.f, 0.f, 0.f, 0.f};
        gemm_pass<2, 96, 1000, 0>(slotH, p.WsT3, 4096, 0,
                                  ldsA, ldsW, wave, lane, quad, l15, acc);
        #pragma unroll
        for (int mi = 0; mi < 2; ++mi)
          #pragma unroll
          for (int ni = 0; ni < 2; ++ni)
            #pragma unroll
            for (int r = 0; r < 4; ++r) {
              int i = mi * 16 + quad * 4 + r;
              int col = wave * 32 + ni * 16 + l15;
              if (i < Mk) {
                float v = acc[mi][ni][r];
                int gi = row0 + i;
                int b = p.segb[gi], t = p.segt0[gi] + k;
                float* orow = p.out + ((size_t)b * TT + t) * 1216;
                if (col < 32) {
                  v += p.b_prior_stats[col];
                  orow[1120 + col] = v; orow[1152 + col] = v;
                } else if (col < 64) {
                  v = splus(v + p.b_prior_stats[col]) + 0.1f;
                  orow[1184 + col - 32] = v;
                } else if (col < 96) {
                  v += p.b_post_stats[col - 64];
                  orow[512 + col - 64] = v; orow[544 + col - 64] = v;
                  slotS[i * 32 + (col - 64)] = v;
                } else {
                  v = splus(v + p.b_post_stats[col - 64]) + 0.1f;
                  orow[576 + col - 96] = v;
                }
              }
            }
      }
      __syncthreads();
    }
  }
}

extern "C" void kernel_launch(void* const* d_in, const int* in_sizes, int n_in,
                              void* d_out, int out_size, void* d_ws, size_t ws_size,
                              hipStream_t stream) {
  P p;
  p.obs = (const float*)d_in[0];
  p.action = (const float*)d_in[1];
  p.is_first = (const int*)d_in[2];
  p.w_prior_in = (const float*)d_in[3];
  p.g_prior_in = (const float*)d_in[4];
  p.bb_prior_in = (const float*)d_in[5];
  p.w_gru = (const float*)d_in[6];
  p.g_gru = (const float*)d_in[7];
  p.bb_gru = (const float*)d_in[8];
  p.w_prior_out = (const float*)d_in[9];
  p.g_prior_out = (const float*)d_in[10];
  p.bb_prior_out = (const float*)d_in[11];
  p.w_prior_stats = (const float*)d_in[12];
  p.b_prior_stats = (const float*)d_in[13];
  p.w_post = (const float*)d_in[14];
  p.g_post = (const float*)d_in[15];
  p.bb_post = (const float*)d_in[16];
  p.w_post_stats = (const float*)d_in[17];
  p.b_post_stats = (const float*)d_in[18];
  p.initial_deter = (const float*)d_in[19];
  p.out = (float*)d_out;

  char* w = (char*)d_ws;
  auto alloc = [&](size_t bytes) -> char* {
    char* r = w; w += (bytes + 255) & ~(size_t)255; return r;
  };
  p.WgT3 = (u16*)alloc((size_t)1536 * 3072 * 2);
  p.W2T3 = (u16*)alloc((size_t)1024 * 1632 * 2);
  p.WsT3 = (u16*)alloc((size_t)128 * 3072 * 2);
  p.deter0 = (float*)alloc(512 * 4);
  p.init_mean = (float*)alloc(32 * 4);
  p.segb = (int*)alloc((size_t)65536 * 4);
  p.segt0 = (int*)alloc((size_t)65536 * 4);
  p.nact = (int*)alloc(257 * 4);
  p.qhead = (int*)alloc(256);
  size_t used = (size_t)(w - (char*)d_ws);
  size_t avail = ws_size > used ? ws_size - used : 0;
  // per-block slot: arow 204800 + h2 196608 + gates 196608 + hraw 131072
  //               + deter 65536 + stoch 4096 = 798720 B (+ alignment)
  size_t slot = 800768;
  long long nb = (long long)(avail / slot);
  if (nb > 256) nb = 256;
  if (nb < 1) nb = 1;
  p.NB = (int)nb;
  p.arow = (u16*)alloc((size_t)p.NB * 204800);
  p.h2 = (u16*)alloc((size_t)p.NB * 196608);
  p.gates = (float*)alloc((size_t)p.NB * 196608);
  p.hraw = (float*)alloc((size_t)p.NB * 131072);
  p.deter = (float*)alloc((size_t)p.NB * 65536);
  p.stoch = (float*)alloc((size_t)p.NB * 4096);

  k_weights<<<dim3(256), dim3(256), 0, stream>>>(p);
  k_init_state<<<dim3(1), dim3(256), 0, stream>>>(p);
  k_segments<<<dim3(1), dim3(256), 0, stream>>>(p);
  k_main<<<dim3(p.NB), dim3(BDIM), 0, stream>>>(p);
}

// Round 2
// 12472.555 us; speedup vs baseline: 1.1148x; 1.1148x over previous
//
#include <hip/hip_runtime.h>

#define TT 256
#define BDIM 256
#define MT 32

typedef unsigned short u16;
typedef unsigned int u32;
typedef __attribute__((ext_vector_type(8))) short bf16x8;
typedef __attribute__((ext_vector_type(4))) float f32x4;

// async global->LDS, 16B/lane; LDS dest is wave-uniform base + lane*16
#define GLL(g, l) __builtin_amdgcn_global_load_lds( \
    (const __attribute__((address_space(1))) void*)(g), \
    (__attribute__((address_space(3))) void*)(l), 16, 0, 0)

struct P {
  const float* obs; const float* action; const int* is_first;
  const float* w_prior_in; const float* g_prior_in; const float* bb_prior_in;
  const float* w_gru; const float* g_gru; const float* bb_gru;
  const float* w_prior_out; const float* g_prior_out; const float* bb_prior_out;
  const float* w_prior_stats; const float* b_prior_stats;
  const float* w_post; const float* g_post; const float* bb_post;
  const float* w_post_stats; const float* b_post_stats;
  const float* initial_deter;
  float* out;
  // weights: blocked per 32-k chunk [kc][N][32] u16, XOR-swizzled rows
  u16 *WgT3;    // 96 kc x 1536 n   K-order [deter3(1536) | h3(1536)], planes W:[hi|hi|lo]
  u16 *W2T3;    // 51 kc x 1024 n   K-order [deter3(1536) | obs3(96)]
  u16 *WsT3;    // 96 kc x 128 n    K-order h2 planes
  float *deter0, *init_mean;
  int *segb, *segt0, *nact;
  // per-block slots
  u16 *arow;    // [NB][100][1024] u16 swizzled chunks: d3 ch0-47, h3 ch48-95, obs3 ch96-98
  u16 *h2;      // [NB][96][1024]
  float *gates; // [NB][32][1536]
  float *hraw;  // [NB][32][1024]
  float *deter; // [NB][32][512]
  float *stoch; // [NB][32][32]
  int NB;
};

__device__ __forceinline__ float b2f(u16 u) {
  union { float f; u32 i; } v; v.i = ((u32)u) << 16; return v.f;
}
__device__ __forceinline__ u16 f2b(float f) {
  union { float f; u32 i; } v; v.f = f;
  u32 r = v.i + 0x7FFF + ((v.i >> 16) & 1);   // RNE
  return (u16)(r >> 16);
}
__device__ __forceinline__ float sigm(float x) { return 1.f / (1.f + __expf(-x)); }
__device__ __forceinline__ float splus(float x) { return x > 15.f ? x : log1pf(__expf(x)); }

// write one u16 at logical (row, kk) into a swizzled chunked buffer
__device__ __forceinline__ void awr(u16* base, int row, int kk, u16 v) {
  base[((kk >> 5) << 10) + (((row << 5) + (kk & 31)) ^ ((row & 7) << 3))] = v;
}

// ---- prior_in head: h = silu(ln(x @ Wpi)); writes h3 planes (cols 1536..3071) ----
__device__ __forceinline__ void h_from_x(const P& p, u16* slotA, int i, float xv, int lane) {
  float a0[8];
  #pragma unroll
  for (int c = 0; c < 8; ++c) a0[c] = 0.f;
  #pragma unroll 4
  for (int j = 0; j < 36; ++j) {
    float s = __shfl(xv, j, 64);
    const float* wr = p.w_prior_in + j * 512 + lane;
    #pragma unroll
    for (int c = 0; c < 8; ++c) a0[c] = fmaf(s, wr[c << 6], a0[c]);
  }
  float sm = 0.f, sq = 0.f;
  #pragma unroll
  for (int c = 0; c < 8; ++c) { sm += a0[c]; sq += a0[c] * a0[c]; }
  #pragma unroll
  for (int o = 32; o; o >>= 1) { sm += __shfl_xor(sm, o); sq += __shfl_xor(sq, o); }
  float m = sm * (1.f / 512.f);
  float rs = rsqrtf(sq * (1.f / 512.f) - m * m + 1e-3f);
  #pragma unroll
  for (int c = 0; c < 8; ++c) {
    int col = lane + (c << 6);
    float v = (a0[c] - m) * rs * p.g_prior_in[col] + p.bb_prior_in[col];
    v = v * sigm(v);
    u16 hi = f2b(v); u16 lo = f2b(v - b2f(hi));
    awr(slotA, i, 1536 + col, hi);
    awr(slotA, i, 2048 + col, lo);
    awr(slotA, i, 2560 + col, hi);
  }
}

// ================= prep kernels =================
__global__ void k_weights(P p) {
  const int E1 = 1536 * 3072, E2 = 1024 * 1632, E3 = 128 * 3072;
  const int total = E1 + E2 + E3;
  for (int idx = blockIdx.x * blockDim.x + threadIdx.x; idx < total;
       idx += gridDim.x * blockDim.x) {
    float w; u16* base; size_t dstIdx; int lo_sel;
    if (idx < E1) {                       // Wg: n in [0,1536), kk in [0,3072)
      int n = idx / 3072, kk = idx - n * 3072;
      int sub = (kk < 1536) ? kk : kk - 1536;
      int c = sub & 511, pl = sub >> 9;
      w = (kk < 1536) ? p.w_gru[(512 + c) * 1536 + n]   // deter rows
                      : p.w_gru[c * 1536 + n];          // h rows
      lo_sel = (pl == 2);
      base = p.WgT3;
      dstIdx = (size_t)(kk >> 5) * 49152 + (((n << 5) + (kk & 31)) ^ ((n & 7) << 3));
    } else if (idx < E1 + E2) {           // W2: n in [0,1024), kk in [0,1632)
      int t = idx - E1;
      int n = t / 1632, kk = t - n * 1632;
      if (kk < 1536) {
        int c = kk & 511, pl = kk >> 9;
        w = (n < 512) ? p.w_prior_out[c * 512 + n] : p.w_post[c * 512 + (n - 512)];
        lo_sel = (pl == 2);
      } else {
        int j = kk - 1536; int c = j & 31, pl = j >> 5;
        w = (n >= 512 && c < 18) ? p.w_post[(512 + c) * 512 + (n - 512)] : 0.f;
        lo_sel = (pl == 2);
      }
      base = p.W2T3;
      dstIdx = (size_t)(kk >> 5) * 32768 + (((n << 5) + (kk & 31)) ^ ((n & 7) << 3));
    } else {                              // Ws: n in [0,128), kk in [0,3072)
      int t = idx - E1 - E2;
      int n = t / 3072, kk = t - n * 3072;
      int c = kk & 1023, pl = kk >> 10;
      if (n < 64) w = (c < 512) ? p.w_prior_stats[c * 64 + n] : 0.f;
      else        w = (c >= 512) ? p.w_post_stats[(c - 512) * 64 + (n - 64)] : 0.f;
      lo_sel = (pl == 2);
      base = p.WsT3;
      dstIdx = (size_t)(kk >> 5) * 4096 + (((n << 5) + (kk & 31)) ^ ((n & 7) << 3));
    }
    u16 hi = f2b(w); u16 lo = f2b(w - b2f(hi));
    base[dstIdx] = lo_sel ? lo : hi;
  }
}

__global__ void k_init_state(P p) {
  __shared__ float d0s[512], tmp[512], red[256];
  int tid = threadIdx.x;
  for (int n = tid; n < 512; n += 256) { d0s[n] = tanhf(p.initial_deter[n]); p.deter0[n] = d0s[n]; }
  __syncthreads();
  for (int n = tid; n < 512; n += 256) {
    float s = 0.f;
    for (int d = 0; d < 512; ++d) s = fmaf(d0s[d], p.w_prior_out[d * 512 + n], s);
    tmp[n] = s;
  }
  __syncthreads();
  float ls = 0.f, lq = 0.f;
  for (int n = tid; n < 512; n += 256) { ls += tmp[n]; lq += tmp[n] * tmp[n]; }
  red[tid] = ls; __syncthreads();
  for (int s = 128; s; s >>= 1) { if (tid < s) red[tid] += red[tid + s]; __syncthreads(); }
  float m = red[0] * (1.f / 512.f); __syncthreads();
  red[tid] = lq; __syncthreads();
  for (int s = 128; s; s >>= 1) { if (tid < s) red[tid] += red[tid + s]; __syncthreads(); }
  float rs = rsqrtf(red[0] * (1.f / 512.f) - m * m + 1e-3f); __syncthreads();
  for (int n = tid; n < 512; n += 256) {
    float h = (tmp[n] - m) * rs * p.g_prior_out[n] + p.bb_prior_out[n];
    tmp[n] = h * sigm(h);
  }
  __syncthreads();
  if (tid < 32) {
    float s = 0.f;
    for (int d = 0; d < 512; ++d) s = fmaf(tmp[d], p.w_prior_stats[d * 64 + tid], s);
    p.init_mean[tid] = s + p.b_prior_stats[tid];
  }
}

__global__ void k_segments(P p) {
  __shared__ int hist[257], off[258], cur[257];
  int tid = threadIdx.x;
  for (int i = tid; i < 257; i += 256) hist[i] = 0;
  __syncthreads();
  int b = tid;
  { int t = 0;
    while (t < TT) {
      int t0 = t; t++;
      while (t < TT && p.is_first[b * TT + t] == 0) t++;
      atomicAdd(&hist[t - t0], 1);
    } }
  __syncthreads();
  if (tid == 0) {
    int run = 0;
    for (int len = 256; len >= 0; --len) { off[len] = run; run += hist[len]; }
  }
  __syncthreads();
  for (int i = tid; i < 257; i += 256) { cur[i] = off[i]; p.nact[i] = off[i]; }
  __syncthreads();
  { int t = 0;
    while (t < TT) {
      int t0 = t; t++;
      while (t < TT && p.is_first[b * TT + t] == 0) t++;
      int idx = atomicAdd(&cur[t - t0], 1);
      p.segb[idx] = b; p.segt0[idx] = t0;
    } }
}

// ---- block-local GEMM pass: C(32 x NI*64) += A(32 x NSTEPS*32) * W^T ----
// 4-deep pipeline, lead-3, counted vmcnt with peeled tail.
// per-stage per-wave GLL count: wave<2 -> NI+1 (incl A), else NI.
template<int NI, int NSTEPS, int JAT, int JD>
__device__ __forceinline__ void gemm_pass(
    const u16* __restrict__ aBase, const u16* __restrict__ wBase,
    int wStride, int n0, u16* ldsA, u16* ldsW,
    int wave, int lane, int quad, int l15, f32x4 (&acc)[2][NI]) {

  auto stage = [&](int st, int buf) {
    int ach = (JAT < NSTEPS && st >= JAT) ? st + JD : st;
    const u16* aSrc = aBase + ((size_t)ach << 10) + (wave << 9) + (lane << 3);
    const u16* wSrc = wBase + (size_t)st * wStride + n0 * 32 + (lane << 3);
    if (wave < 2) GLL(aSrc, ldsA + (buf << 10) + (wave << 9));
    #pragma unroll
    for (int gg = 0; gg < NI; ++gg) {
      int g = wave * NI + gg;
      GLL(wSrc + (g << 9), ldsW + (buf << 13) + (g << 9));
    }
  };
  auto compute = [&](int buf) {
    const u16* A = ldsA + (buf << 10);
    const u16* W = ldsW + (buf << 13);
    int xr = (l15 & 7) << 3;
    bf16x8 af[2];
    #pragma unroll
    for (int mi = 0; mi < 2; ++mi) {
      int r = mi * 16 + l15;
      af[mi] = *(const bf16x8*)&A[((r << 5) + (quad << 3)) ^ xr];
    }
    #pragma unroll
    for (int ni = 0; ni < NI; ++ni) {
      int rr = wave * (NI * 16) + ni * 16 + l15;
      bf16x8 bv = *(const bf16x8*)&W[((rr << 5) + (quad << 3)) ^ xr];
      #pragma unroll
      for (int mi = 0; mi < 2; ++mi)
        acc[mi][ni] = __builtin_amdgcn_mfma_f32_16x16x32_bf16(af[mi], bv, acc[mi][ni], 0, 0, 0);
    }
  };

  stage(0, 0); stage(1, 1); stage(2, 2);
  int b4 = 0;
  for (int st = 0; st < NSTEPS; ++st) {
    // wait for stage(st); leave newer stages in flight (counted, never drain mid-loop)
    if (st < NSTEPS - 2) {
      if (wave < 2) asm volatile("s_waitcnt vmcnt(%0)" :: "i"(2 * (NI + 1)) : "memory");
      else          asm volatile("s_waitcnt vmcnt(%0)" :: "i"(2 * NI) : "memory");
    } else if (st == NSTEPS - 2) {
      if (wave < 2) asm volatile("s_waitcnt vmcnt(%0)" :: "i"(NI + 1) : "memory");
      else          asm volatile("s_waitcnt vmcnt(%0)" :: "i"(NI) : "memory");
    } else {
      asm volatile("s_waitcnt vmcnt(0)" ::: "memory");
    }
    __builtin_amdgcn_s_barrier();
    __builtin_amdgcn_sched_barrier(0);
    if (st + 3 < NSTEPS) { int bs = (b4 + 3) & 3; stage(st + 3, bs); }
    compute(b4);
    b4 = (b4 + 1) & 3;
  }
}

// ================= main persistent kernel: static XCD-aligned tile schedule =================
__global__ void __launch_bounds__(BDIM, 1) k_main(P p) {
  __shared__ u16 lds[36864];   // A: 4x1024 u16 (8KB), W: 4x8192 u16 (64KB)
  const int tid = threadIdx.x;
  const int wave = tid >> 6, lane = tid & 63, quad = lane >> 4, l15 = lane & 15;
  u16* ldsA = lds;
  u16* ldsW = lds + 4096;
  const int blk = blockIdx.x;
  u16* slotA = p.arow + (size_t)blk * 102400;
  u16* slotH = p.h2 + (size_t)blk * 98304;
  float* slotG = p.gates + (size_t)blk * 49152;
  float* slotR = p.hraw + (size_t)blk * 32768;
  float* slotD = p.deter + (size_t)blk * 16384;
  float* slotS = p.stoch + (size_t)blk * 1024;
  const int S_total = p.nact[0];
  const int ntiles = (S_total + MT - 1) >> 5;
  const int gmax = (ntiles + 255) & ~255;

  // static schedule: round r = g>>8; within round, XCD x (=blk&7 under %8 dispatch)
  // gets 32 CONSECUTIVE sorted tiles -> same-XCD blocks stream the same weight
  // window at the same k (L2 sharing). Serpentine balances length gradient.
  for (int g = blk; g < gmax; g += p.NB) {
    int r = g >> 8, w = g & 255;
    int x = w & 7; if (r & 1) x = 7 - x;
    int t = (r << 8) + (x << 5) + ((w >> 3) & 31);
    if (t >= ntiles) continue;
    int row0 = t << 5;
    int nr0 = S_total - row0; if (nr0 > MT) nr0 = MT;

    for (int k = 0;; ++k) {
      int Mk = p.nact[k] - row0; if (Mk > nr0) Mk = nr0;
      if (Mk <= 0) break;

      // ---- A: state init (k==0) + prior_in head ----
      for (int i = wave; i < Mk; i += 4) {
        int gi = row0 + i;
        int b = p.segb[gi], t0 = p.segt0[gi];
        float xv = 0.f;
        if (k == 0) {
          #pragma unroll
          for (int c = 0; c < 8; ++c) {
            int d = lane + (c << 6);
            float v = p.deter0[d];
            slotD[i * 512 + d] = v;
            u16 hi = f2b(v); u16 lo = f2b(v - b2f(hi));
            awr(slotA, i, d, hi);
            awr(slotA, i, 512 + d, lo);
            awr(slotA, i, 1024 + d, hi);
          }
          int ff = p.is_first[b * TT + t0];
          if (lane < 32) xv = p.init_mean[lane];
          else if (lane < 36) xv = (ff > 0) ? 0.f : p.action[((size_t)b * TT + t0) * 4 + (lane - 32)];
        } else {
          if (lane < 32) xv = slotS[i * 32 + lane];
          else if (lane < 36) xv = p.action[((size_t)b * TT + t0 + k) * 4 + (lane - 32)];
        }
        h_from_x(p, slotA, i, xv, lane);
      }
      __syncthreads();

      // ---- B: gates = arow[d3|h3] @ WgT3   (32 x 1536, K3=3072) ----
      for (int np = 0; np < 6; ++np) {
        f32x4 acc[2][4];
        #pragma unroll
        for (int a = 0; a < 2; ++a)
          #pragma unroll
          for (int bq = 0; bq < 4; ++bq) acc[a][bq] = f32x4{0.f, 0.f, 0.f, 0.f};
        gemm_pass<4, 96, 1000, 0>(slotA, p.WgT3, 49152, np * 256,
                                  ldsA, ldsW, wave, lane, quad, l15, acc);
        #pragma unroll
        for (int mi = 0; mi < 2; ++mi)
          #pragma unroll
          for (int ni = 0; ni < 4; ++ni)
            #pragma unroll
            for (int rr = 0; rr < 4; ++rr)
              slotG[(mi * 16 + quad * 4 + rr) * 1536 + np * 256 + wave * 64 + ni * 16 + l15]
                  = acc[mi][ni][rr];
      }
      __syncthreads();

      // ---- C: LN(gates) -> GRU -> deter', d3/obs3 refresh, out-deter ----
      for (int i = wave; i < Mk; i += 4) {
        const float* grow = slotG + i * 1536;
        float g24[24];
        float sm = 0.f, sq = 0.f;
        #pragma unroll
        for (int c = 0; c < 24; ++c) {
          g24[c] = grow[lane + (c << 6)];
          sm += g24[c]; sq += g24[c] * g24[c];
        }
        #pragma unroll
        for (int o = 32; o; o >>= 1) { sm += __shfl_xor(sm, o); sq += __shfl_xor(sq, o); }
        float m = sm * (1.f / 1536.f);
        float rs = rsqrtf(sq * (1.f / 1536.f) - m * m + 1e-3f);
        int gi = row0 + i;
        int b = p.segb[gi], tt = p.segt0[gi] + k;
        float* orow = p.out + ((size_t)b * TT + tt) * 1216;
        #pragma unroll
        for (int c = 0; c < 8; ++c) {
          int d = lane + (c << 6);
          float gr = (g24[c] - m) * rs * p.g_gru[d] + p.bb_gru[d];
          float gc = (g24[c + 8] - m) * rs * p.g_gru[512 + d] + p.bb_gru[512 + d];
          float gu = (g24[c + 16] - m) * rs * p.g_gru[1024 + d] + p.bb_gru[1024 + d];
          float r_ = sigm(gr);
          float u_ = sigm(gu - 1.0f);
          float rc = r_ * gc;
          float cand = rc * sigm(rc);
          float dp = slotD[i * 512 + d];
          float dn = u_ * cand + (1.f - u_) * dp;
          slotD[i * 512 + d] = dn;
          orow[d] = dn; orow[608 + d] = dn;
          u16 hi = f2b(dn); u16 lo = f2b(dn - b2f(hi));
          awr(slotA, i, d, hi);
          awr(slotA, i, 512 + d, lo);
          awr(slotA, i, 1024 + d, hi);
        }
        if (lane < 32) {
          float ov = (lane < 18) ? p.obs[((size_t)b * TT + tt) * 18 + lane] : 0.f;
          u16 hi = f2b(ov); u16 lo = f2b(ov - b2f(hi));
          awr(slotA, i, 3072 + lane, hi);
          awr(slotA, i, 3104 + lane, lo);
          awr(slotA, i, 3136 + lane, hi);
        }
      }
      __syncthreads();

      // ---- D: hraw = arow[d3|obs3] @ W2T3   (32 x 1024, K3=1632) ----
      for (int np = 0; np < 4; ++np) {
        f32x4 acc[2][4];
        #pragma unroll
        for (int a = 0; a < 2; ++a)
          #pragma unroll
          for (int bq = 0; bq < 4; ++bq) acc[a][bq] = f32x4{0.f, 0.f, 0.f, 0.f};
        gemm_pass<4, 51, 48, 48>(slotA, p.W2T3, 32768, np * 256,
                                 ldsA, ldsW, wave, lane, quad, l15, acc);
        #pragma unroll
        for (int mi = 0; mi < 2; ++mi)
          #pragma unroll
          for (int ni = 0; ni < 4; ++ni)
            #pragma unroll
            for (int rr = 0; rr < 4; ++rr)
              slotR[(mi * 16 + quad * 4 + rr) * 1024 + np * 256 + wave * 64 + ni * 16 + l15]
                  = acc[mi][ni][rr];
      }
      __syncthreads();

      // ---- E: two LNs + silu -> h2 planes ----
      for (int i = wave; i < Mk; i += 4) {
        #pragma unroll
        for (int hh = 0; hh < 2; ++hh) {
          const float* hb = slotR + i * 1024 + (hh << 9);
          const float* gv = hh ? p.g_post : p.g_prior_out;
          const float* bv = hh ? p.bb_post : p.bb_prior_out;
          float v[8];
          float sm = 0.f, sq = 0.f;
          #pragma unroll
          for (int c = 0; c < 8; ++c) {
            v[c] = hb[lane + (c << 6)];
            sm += v[c]; sq += v[c] * v[c];
          }
          #pragma unroll
          for (int o = 32; o; o >>= 1) { sm += __shfl_xor(sm, o); sq += __shfl_xor(sq, o); }
          float m = sm * (1.f / 512.f);
          float rs = rsqrtf(sq * (1.f / 512.f) - m * m + 1e-3f);
          #pragma unroll
          for (int c = 0; c < 8; ++c) {
            int d = lane + (c << 6);
            float xx = (v[c] - m) * rs * gv[d] + bv[d];
            xx = xx * sigm(xx);
            int col = (hh << 9) + d;
            u16 hi = f2b(xx); u16 lo = f2b(xx - b2f(hi));
            awr(slotH, i, col, hi);
            awr(slotH, i, 1024 + col, lo);
            awr(slotH, i, 2048 + col, hi);
          }
        }
      }
      __syncthreads();

      // ---- F: stats = h2 @ WsT3 (32 x 128, K3=3072) + epilogue ----
      {
        f32x4 acc[2][2];
        #pragma unroll
        for (int a = 0; a < 2; ++a)
          #pragma unroll
          for (int bq = 0; bq < 2; ++bq) acc[a][bq] = f32x4{0.f, 0.f, 0.f, 0.f};
        gemm_pass<2, 96, 1000, 0>(slotH, p.WsT3, 4096, 0,
                                  ldsA, ldsW, wave, lane, quad, l15, acc);
        #pragma unroll
        for (int mi = 0; mi < 2; ++mi)
          #pragma unroll
          for (int ni = 0; ni < 2; ++ni)
            #pragma unroll
            for (int rr = 0; rr < 4; ++rr) {
              int i = mi * 16 + quad * 4 + rr;
              int col = wave * 32 + ni * 16 + l15;
              if (i < Mk) {
                float v = acc[mi][ni][rr];
                int gi = row0 + i;
                int b = p.segb[gi], tt = p.segt0[gi] + k;
                float* orow = p.out + ((size_t)b * TT + tt) * 1216;
                if (col < 32) {
                  v += p.b_prior_stats[col];
                  orow[1120 + col] = v; orow[1152 + col] = v;
                } else if (col < 64) {
                  v = splus(v + p.b_prior_stats[col]) + 0.1f;
                  orow[1184 + col - 32] = v;
                } else if (col < 96) {
                  v += p.b_post_stats[col - 64];
                  orow[512 + col - 64] = v; orow[544 + col - 64] = v;
                  slotS[i * 32 + (col - 64)] = v;
                } else {
                  v = splus(v + p.b_post_stats[col - 64]) + 0.1f;
                  orow[576 + col - 96] = v;
                }
              }
            }
      }
      __syncthreads();
    }
  }
}

extern "C" void kernel_launch(void* const* d_in, const int* in_sizes, int n_in,
                              void* d_out, int out_size, void* d_ws, size_t ws_size,
                              hipStream_t stream) {
  P p;
  p.obs = (const float*)d_in[0];
  p.action = (const float*)d_in[1];
  p.is_first = (const int*)d_in[2];
  p.w_prior_in = (const float*)d_in[3];
  p.g_prior_in = (const float*)d_in[4];
  p.bb_prior_in = (const float*)d_in[5];
  p.w_gru = (const float*)d_in[6];
  p.g_gru = (const float*)d_in[7];
  p.bb_gru = (const float*)d_in[8];
  p.w_prior_out = (const float*)d_in[9];
  p.g_prior_out = (const float*)d_in[10];
  p.bb_prior_out = (const float*)d_in[11];
  p.w_prior_stats = (const float*)d_in[12];
  p.b_prior_stats = (const float*)d_in[13];
  p.w_post = (const float*)d_in[14];
  p.g_post = (const float*)d_in[15];
  p.bb_post = (const float*)d_in[16];
  p.w_post_stats = (const float*)d_in[17];
  p.b_post_stats = (const float*)d_in[18];
  p.initial_deter = (const float*)d_in[19];
  p.out = (float*)d_out;

  char* w = (char*)d_ws;
  auto alloc = [&](size_t bytes) -> char* {
    char* r = w; w += (bytes + 255) & ~(size_t)255; return r;
  };
  p.WgT3 = (u16*)alloc((size_t)1536 * 3072 * 2);
  p.W2T3 = (u16*)alloc((size_t)1024 * 1632 * 2);
  p.WsT3 = (u16*)alloc((size_t)128 * 3072 * 2);
  p.deter0 = (float*)alloc(512 * 4);
  p.init_mean = (float*)alloc(32 * 4);
  p.segb = (int*)alloc((size_t)65536 * 4);
  p.segt0 = (int*)alloc((size_t)65536 * 4);
  p.nact = (int*)alloc(257 * 4);
  size_t used = (size_t)(w - (char*)d_ws);
  size_t avail = ws_size > used ? ws_size - used : 0;
  // per-block slot: arow 204800 + h2 196608 + gates 196608 + hraw 131072
  //               + deter 65536 + stoch 4096 = 798720 B (+ alignment)
  size_t slot = 800768;
  long long nb = (long long)(avail / slot);
  if (nb > 256) nb = 256;
  if (nb < 1) nb = 1;
  p.NB = (int)nb;
  p.arow = (u16*)alloc((size_t)p.NB * 204800);
  p.h2 = (u16*)alloc((size_t)p.NB * 196608);
  p.gates = (float*)alloc((size_t)p.NB * 196608);
  p.hraw = (float*)alloc((size_t)p.NB * 131072);
  p.deter = (float*)alloc((size_t)p.NB * 65536);
  p.stoch = (float*)alloc((size_t)p.NB * 4096);

  k_weights<<<dim3(256), dim3(256), 0, stream>>>(p);
  k_init_state<<<dim3(1), dim3(256), 0, stream>>>(p);
  k_segments<<<dim3(1), dim3(256), 0, stream>>>(p);
  k_main<<<dim3(p.NB), dim3(BDIM), 0, stream>>>(p);
}

// Round 3
// 8923.766 us; speedup vs baseline: 1.5581x; 1.3977x over previous
//
#include <hip/hip_runtime.h>

#define TT 256
#define BDIM 256
#define MT 32

typedef unsigned short u16;
typedef unsigned int u32;
typedef __attribute__((ext_vector_type(8))) short bf16x8;
typedef __attribute__((ext_vector_type(4))) float f32x4;

// async global->LDS, 16B/lane; LDS dest is wave-uniform base + lane*16
#define GLL(g, l) __builtin_amdgcn_global_load_lds( \
    (const __attribute__((address_space(1))) void*)(g), \
    (__attribute__((address_space(3))) void*)(l), 16, 0, 0)

struct P {
  const float* obs; const float* action; const int* is_first;
  const float* w_prior_in; const float* g_prior_in; const float* bb_prior_in;
  const float* w_gru; const float* g_gru; const float* bb_gru;
  const float* w_prior_out; const float* g_prior_out; const float* bb_prior_out;
  const float* w_prior_stats; const float* b_prior_stats;
  const float* w_post; const float* g_post; const float* bb_post;
  const float* w_post_stats; const float* b_post_stats;
  const float* initial_deter;
  float* out;
  // 2-plane weights, image-blocked for GLL: image = [hi RPP rows | lo RPP rows] x 32 k,
  // rows XOR-swizzled. 3 MFMA products per chunk-pair give full split-bf16 accuracy.
  u16 *WgT3;    // 192 images (pc*6+np) x 16384 u16; K-order [deter(512)|h(512)]
  u16 *W2T3;    // 68 images (pc*4+np) x 16384;      K-order [deter(512)|obs(32)]
  u16 *WsT3;    // 32 images (pc) x 8192;            K = h2(1024)
  float *deter0, *init_mean;
  int *segb, *segt0, *nact;
  // per-block slots
  u16 *arow;    // [NB][33 imgs][2048] u16: pc 0-15 deter, 16 obs, 17-32 h
  u16 *h2;      // [NB][32 imgs][2048]
  float *gates; // [NB][32][1536]
  float *hraw;  // [NB][32][1024]
  float *deter; // [NB][32][512]
  float *stoch; // [NB][32][32]
  int NB;
};

__device__ __forceinline__ float b2f(u16 u) {
  union { float f; u32 i; } v; v.i = ((u32)u) << 16; return v.f;
}
__device__ __forceinline__ u16 f2b(float f) {
  union { float f; u32 i; } v; v.f = f;
  u32 r = v.i + 0x7FFF + ((v.i >> 16) & 1);   // RNE
  return (u16)(r >> 16);
}
__device__ __forceinline__ float sigm(float x) { return 1.f / (1.f + __expf(-x)); }
__device__ __forceinline__ float splus(float x) { return x > 15.f ? x : log1pf(__expf(x)); }

// write hi/lo planes of logical (row i, col kk) into a 2-plane image buffer
__device__ __forceinline__ void awr2(u16* base, int i, int kk, u16 hi, u16 lo) {
  size_t o = (size_t)(kk >> 5) << 11;
  int sw = ((i << 5) + (kk & 31)) ^ ((i & 7) << 3);
  base[o + sw] = hi;
  base[o + 1024 + sw] = lo;   // lo-plane row 32+i
}

// ---- prior_in head: h = silu(ln(x @ Wpi)); writes h planes (A cols 544..1055) ----
__device__ __forceinline__ void h_from_x(const P& p, u16* slotA, int i, float xv, int lane) {
  float a0[8];
  #pragma unroll
  for (int c = 0; c < 8; ++c) a0[c] = 0.f;
  #pragma unroll 4
  for (int j = 0; j < 36; ++j) {
    float s = __shfl(xv, j, 64);
    const float* wr = p.w_prior_in + j * 512 + lane;
    #pragma unroll
    for (int c = 0; c < 8; ++c) a0[c] = fmaf(s, wr[c << 6], a0[c]);
  }
  float sm = 0.f, sq = 0.f;
  #pragma unroll
  for (int c = 0; c < 8; ++c) { sm += a0[c]; sq += a0[c] * a0[c]; }
  #pragma unroll
  for (int o = 32; o; o >>= 1) { sm += __shfl_xor(sm, o); sq += __shfl_xor(sq, o); }
  float m = sm * (1.f / 512.f);
  float rs = rsqrtf(sq * (1.f / 512.f) - m * m + 1e-3f);
  #pragma unroll
  for (int c = 0; c < 8; ++c) {
    int col = lane + (c << 6);
    float v = (a0[c] - m) * rs * p.g_prior_in[col] + p.bb_prior_in[col];
    v = v * sigm(v);
    u16 hi = f2b(v);
    awr2(slotA, i, 544 + col, hi, f2b(v - b2f(hi)));
  }
}

// ================= prep kernels =================
__global__ void k_weights(P p) {
  const int E1 = 192 * 16384, E2 = 68 * 16384, E3 = 32 * 8192;
  const int total = E1 + E2 + E3;
  for (int idx = blockIdx.x * blockDim.x + threadIdx.x; idx < total;
       idx += gridDim.x * blockDim.x) {
    float w; u16* dst;
    int pl;
    if (idx < E1) {                       // Wg
      int kk = idx & 31, prow = (idx >> 5) & 511, img = idx >> 14;
      int pc = img / 6, np = img - pc * 6;
      pl = prow >> 8;
      int n = np * 256 + (prow & 255), k = (pc << 5) + kk;
      w = (k < 512) ? p.w_gru[(512 + k) * 1536 + n] : p.w_gru[(k - 512) * 1536 + n];
      dst = p.WgT3 + ((size_t)img << 14) + (((prow << 5) + kk) ^ ((prow & 7) << 3));
    } else if (idx < E1 + E2) {           // W2
      int t = idx - E1;
      int kk = t & 31, prow = (t >> 5) & 511, img = t >> 14;
      int pc = img >> 2, np = img & 3;
      pl = prow >> 8;
      int n = np * 256 + (prow & 255), k = (pc << 5) + kk;
      if (k < 512) w = (n < 512) ? p.w_prior_out[k * 512 + n] : p.w_post[k * 512 + (n - 512)];
      else { int j = k - 512; w = (n >= 512 && j < 18) ? p.w_post[(512 + j) * 512 + (n - 512)] : 0.f; }
      dst = p.W2T3 + ((size_t)img << 14) + (((prow << 5) + kk) ^ ((prow & 7) << 3));
    } else {                              // Ws
      int t = idx - E1 - E2;
      int kk = t & 31, prow = (t >> 5) & 255, pc = t >> 13;
      pl = prow >> 7;
      int nl = prow & 127, k = (pc << 5) + kk;
      if (nl < 64) w = (k < 512) ? p.w_prior_stats[k * 64 + nl] : 0.f;
      else         w = (k >= 512) ? p.w_post_stats[(k - 512) * 64 + (nl - 64)] : 0.f;
      dst = p.WsT3 + ((size_t)pc << 13) + (((prow << 5) + kk) ^ ((prow & 7) << 3));
    }
    u16 hi = f2b(w);
    *dst = pl ? f2b(w - b2f(hi)) : hi;
  }
}

__global__ void k_init_state(P p) {
  __shared__ float d0s[512], tmp[512], red[256];
  int tid = threadIdx.x;
  for (int n = tid; n < 512; n += 256) { d0s[n] = tanhf(p.initial_deter[n]); p.deter0[n] = d0s[n]; }
  __syncthreads();
  for (int n = tid; n < 512; n += 256) {
    float s = 0.f;
    for (int d = 0; d < 512; ++d) s = fmaf(d0s[d], p.w_prior_out[d * 512 + n], s);
    tmp[n] = s;
  }
  __syncthreads();
  float ls = 0.f, lq = 0.f;
  for (int n = tid; n < 512; n += 256) { ls += tmp[n]; lq += tmp[n] * tmp[n]; }
  red[tid] = ls; __syncthreads();
  for (int s = 128; s; s >>= 1) { if (tid < s) red[tid] += red[tid + s]; __syncthreads(); }
  float m = red[0] * (1.f / 512.f); __syncthreads();
  red[tid] = lq; __syncthreads();
  for (int s = 128; s; s >>= 1) { if (tid < s) red[tid] += red[tid + s]; __syncthreads(); }
  float rs = rsqrtf(red[0] * (1.f / 512.f) - m * m + 1e-3f); __syncthreads();
  for (int n = tid; n < 512; n += 256) {
    float h = (tmp[n] - m) * rs * p.g_prior_out[n] + p.bb_prior_out[n];
    tmp[n] = h * sigm(h);
  }
  __syncthreads();
  if (tid < 32) {
    float s = 0.f;
    for (int d = 0; d < 512; ++d) s = fmaf(tmp[d], p.w_prior_stats[d * 64 + tid], s);
    p.init_mean[tid] = s + p.b_prior_stats[tid];
  }
}

__global__ void k_segments(P p) {
  __shared__ int hist[257], off[258], cur[257];
  int tid = threadIdx.x;
  for (int i = tid; i < 257; i += 256) hist[i] = 0;
  __syncthreads();
  int b = tid;
  { int t = 0;
    while (t < TT) {
      int t0 = t; t++;
      while (t < TT && p.is_first[b * TT + t] == 0) t++;
      atomicAdd(&hist[t - t0], 1);
    } }
  __syncthreads();
  if (tid == 0) {
    int run = 0;
    for (int len = 256; len >= 0; --len) { off[len] = run; run += hist[len]; }
  }
  __syncthreads();
  for (int i = tid; i < 257; i += 256) { cur[i] = off[i]; p.nact[i] = off[i]; }
  __syncthreads();
  { int t = 0;
    while (t < TT) {
      int t0 = t; t++;
      while (t < TT && p.is_first[b * TT + t] == 0) t++;
      int idx = atomicAdd(&cur[t - t0], 1);
      p.segb[idx] = b; p.segt0[idx] = t0;
    } }
}

// ---- block-local GEMM pass: C(32 x NI*64) += A(32 x 32*NSTEPS k) * W^T ----
// 2-plane, 3 products per chunk-pair; 4-buf lead-3 pipeline, counted vmcnt.
// Per stage per wave: 1 A-GLL + 2*(RPP>>6) W-GLLs (uniform across waves).
template<int NI, int NSTEPS, int JAT, int RPP>
__device__ __forceinline__ void gemm_pass(
    const u16* __restrict__ aBase, const u16* __restrict__ wBase, int wStride,
    u16* ldsA, u16* ldsW, int wave, int lane, int quad, int l15,
    f32x4 (&acc)[2][NI]) {
  constexpr int GPW = 1 + (RPP >> 5);     // 9 (RPP=256) or 5 (RPP=128)

  auto stage = [&](int st, int buf) {
    int apc = (st >= JAT) ? st + 1 : st;
    GLL(aBase + ((size_t)apc << 11) + (wave << 9) + (lane << 3),
        ldsA + (buf << 11) + (wave << 9));
    const u16* wS = wBase + (size_t)st * wStride;
    u16* wD = ldsW + (buf << 14);
    #pragma unroll
    for (int pp = 0; pp < 2; ++pp)
      #pragma unroll
      for (int c = 0; c < (RPP >> 6); ++c) {
        int ro = pp * RPP + wave * (RPP >> 2) + (c << 4);
        GLL(wS + (ro << 5) + (lane << 3), wD + (ro << 5));
      }
  };
  auto compute = [&](int buf) {
    const u16* A = ldsA + (buf << 11);
    const u16* W = ldsW + (buf << 14);
    int xr = (l15 & 7) << 3;
    bf16x8 ah[2], al[2];
    #pragma unroll
    for (int mi = 0; mi < 2; ++mi) {
      int r0 = mi * 16 + l15;
      ah[mi] = *(const bf16x8*)&A[((r0 << 5) + (quad << 3)) ^ xr];
      al[mi] = *(const bf16x8*)&A[(((32 + r0) << 5) + (quad << 3)) ^ xr];
    }
    #pragma unroll
    for (int ni = 0; ni < NI; ++ni) {
      int rh = wave * (NI * 16) + ni * 16 + l15;
      bf16x8 wh = *(const bf16x8*)&W[((rh << 5) + (quad << 3)) ^ xr];
      bf16x8 wl = *(const bf16x8*)&W[(((RPP + rh) << 5) + (quad << 3)) ^ xr];
      #pragma unroll
      for (int mi = 0; mi < 2; ++mi) {
        acc[mi][ni] = __builtin_amdgcn_mfma_f32_16x16x32_bf16(ah[mi], wh, acc[mi][ni], 0, 0, 0);
        acc[mi][ni] = __builtin_amdgcn_mfma_f32_16x16x32_bf16(al[mi], wh, acc[mi][ni], 0, 0, 0);
        acc[mi][ni] = __builtin_amdgcn_mfma_f32_16x16x32_bf16(ah[mi], wl, acc[mi][ni], 0, 0, 0);
      }
    }
  };

  stage(0, 0); stage(1, 1); stage(2, 2);
  for (int st = 0; st < NSTEPS; ++st) {
    if (st < NSTEPS - 2)
      asm volatile("s_waitcnt vmcnt(%0)" :: "i"(2 * GPW) : "memory");
    else if (st == NSTEPS - 2)
      asm volatile("s_waitcnt vmcnt(%0)" :: "i"(GPW) : "memory");
    else
      asm volatile("s_waitcnt vmcnt(0)" ::: "memory");
    __builtin_amdgcn_s_barrier();
    __builtin_amdgcn_sched_barrier(0);
    if (st + 3 < NSTEPS) stage(st + 3, (st + 3) & 3);
    compute(st & 3);
  }
}

// ================= main persistent kernel: static XCD-aligned tile schedule =================
__global__ void __launch_bounds__(BDIM, 1) k_main(P p) {
  __shared__ u16 lds[73728];   // A: 4x2048 u16 (16KB), W: 4x16384 u16 (128KB)
  const int tid = threadIdx.x;
  const int wave = tid >> 6, lane = tid & 63, quad = lane >> 4, l15 = lane & 15;
  u16* ldsA = lds;
  u16* ldsW = lds + 8192;
  const int blk = blockIdx.x;
  u16* slotA = p.arow + (size_t)blk * 67584;
  u16* slotH = p.h2 + (size_t)blk * 65536;
  float* slotG = p.gates + (size_t)blk * 49152;
  float* slotR = p.hraw + (size_t)blk * 32768;
  float* slotD = p.deter + (size_t)blk * 16384;
  float* slotS = p.stoch + (size_t)blk * 1024;
  const int S_total = p.nact[0];
  const int ntiles = (S_total + MT - 1) >> 5;
  const int gmax = (ntiles + 255) & ~255;

  // static schedule: within each round of 256, XCD x (=blk&7) gets 32 consecutive
  // sorted tiles -> same-XCD blocks stream the same weight window (L2 sharing).
  for (int g = blk; g < gmax; g += p.NB) {
    int r = g >> 8, w = g & 255;
    int x = w & 7; if (r & 1) x = 7 - x;
    int t = (r << 8) + (x << 5) + ((w >> 3) & 31);
    if (t >= ntiles) continue;
    int row0 = t << 5;
    int nr0 = S_total - row0; if (nr0 > MT) nr0 = MT;

    for (int k = 0;; ++k) {
      int Mk = p.nact[k] - row0; if (Mk > nr0) Mk = nr0;
      if (Mk <= 0) break;

      // ---- A: state init (k==0) + prior_in head ----
      for (int i = wave; i < Mk; i += 4) {
        int gi = row0 + i;
        int b = p.segb[gi], t0 = p.segt0[gi];
        float xv = 0.f;
        if (k == 0) {
          #pragma unroll
          for (int c = 0; c < 8; ++c) {
            int d = lane + (c << 6);
            float v = p.deter0[d];
            slotD[i * 512 + d] = v;
            u16 hi = f2b(v);
            awr2(slotA, i, d, hi, f2b(v - b2f(hi)));
          }
          int ff = p.is_first[b * TT + t0];
          if (lane < 32) xv = p.init_mean[lane];
          else if (lane < 36) xv = (ff > 0) ? 0.f : p.action[((size_t)b * TT + t0) * 4 + (lane - 32)];
        } else {
          if (lane < 32) xv = slotS[i * 32 + lane];
          else if (lane < 36) xv = p.action[((size_t)b * TT + t0 + k) * 4 + (lane - 32)];
        }
        h_from_x(p, slotA, i, xv, lane);
      }
      __syncthreads();

      // ---- B: gates = arow[deter|h] @ Wg  (32 x 1536, K=1024, 2-plane) ----
      for (int np = 0; np < 6; ++np) {
        __syncthreads();                 // WAR: prior pass LDS reads done
        f32x4 acc[2][4];
        #pragma unroll
        for (int a = 0; a < 2; ++a)
          #pragma unroll
          for (int bq = 0; bq < 4; ++bq) acc[a][bq] = f32x4{0.f, 0.f, 0.f, 0.f};
        gemm_pass<4, 32, 16, 256>(slotA, p.WgT3 + np * 16384, 98304,
                                  ldsA, ldsW, wave, lane, quad, l15, acc);
        #pragma unroll
        for (int mi = 0; mi < 2; ++mi)
          #pragma unroll
          for (int ni = 0; ni < 4; ++ni)
            #pragma unroll
            for (int rr = 0; rr < 4; ++rr)
              slotG[(mi * 16 + quad * 4 + rr) * 1536 + np * 256 + wave * 64 + ni * 16 + l15]
                  = acc[mi][ni][rr];
      }
      __syncthreads();

      // ---- C: LN(gates) -> GRU -> deter', deter/obs plane refresh, out-deter ----
      for (int i = wave; i < Mk; i += 4) {
        const float* grow = slotG + i * 1536;
        float g24[24];
        float sm = 0.f, sq = 0.f;
        #pragma unroll
        for (int c = 0; c < 24; ++c) {
          g24[c] = grow[lane + (c << 6)];
          sm += g24[c]; sq += g24[c] * g24[c];
        }
        #pragma unroll
        for (int o = 32; o; o >>= 1) { sm += __shfl_xor(sm, o); sq += __shfl_xor(sq, o); }
        float m = sm * (1.f / 1536.f);
        float rs = rsqrtf(sq * (1.f / 1536.f) - m * m + 1e-3f);
        int gi = row0 + i;
        int b = p.segb[gi], tt = p.segt0[gi] + k;
        float* orow = p.out + ((size_t)b * TT + tt) * 1216;
        #pragma unroll
        for (int c = 0; c < 8; ++c) {
          int d = lane + (c << 6);
          float gr = (g24[c] - m) * rs * p.g_gru[d] + p.bb_gru[d];
          float gc = (g24[c + 8] - m) * rs * p.g_gru[512 + d] + p.bb_gru[512 + d];
          float gu = (g24[c + 16] - m) * rs * p.g_gru[1024 + d] + p.bb_gru[1024 + d];
          float r_ = sigm(gr);
          float u_ = sigm(gu - 1.0f);
          float rc = r_ * gc;
          float cand = rc * sigm(rc);
          float dp = slotD[i * 512 + d];
          float dn = u_ * cand + (1.f - u_) * dp;
          slotD[i * 512 + d] = dn;
          orow[d] = dn; orow[608 + d] = dn;
          u16 hi = f2b(dn);
          awr2(slotA, i, d, hi, f2b(dn - b2f(hi)));
        }
        if (lane < 32) {
          float ov = (lane < 18) ? p.obs[((size_t)b * TT + tt) * 18 + lane] : 0.f;
          u16 hi = f2b(ov);
          awr2(slotA, i, 512 + lane, hi, f2b(ov - b2f(hi)));
        }
      }
      __syncthreads();

      // ---- D: hraw = arow[deter|obs] @ W2  (32 x 1024, K=544, 2-plane) ----
      for (int np = 0; np < 4; ++np) {
        __syncthreads();
        f32x4 acc[2][4];
        #pragma unroll
        for (int a = 0; a < 2; ++a)
          #pragma unroll
          for (int bq = 0; bq < 4; ++bq) acc[a][bq] = f32x4{0.f, 0.f, 0.f, 0.f};
        gemm_pass<4, 17, 1000, 256>(slotA, p.W2T3 + np * 16384, 65536,
                                    ldsA, ldsW, wave, lane, quad, l15, acc);
        #pragma unroll
        for (int mi = 0; mi < 2; ++mi)
          #pragma unroll
          for (int ni = 0; ni < 4; ++ni)
            #pragma unroll
            for (int rr = 0; rr < 4; ++rr)
              slotR[(mi * 16 + quad * 4 + rr) * 1024 + np * 256 + wave * 64 + ni * 16 + l15]
                  = acc[mi][ni][rr];
      }
      __syncthreads();

      // ---- E: two LNs + silu -> h2 planes ----
      for (int i = wave; i < Mk; i += 4) {
        #pragma unroll
        for (int hh = 0; hh < 2; ++hh) {
          const float* hb = slotR + i * 1024 + (hh << 9);
          const float* gv = hh ? p.g_post : p.g_prior_out;
          const float* bv = hh ? p.bb_post : p.bb_prior_out;
          float v[8];
          float sm = 0.f, sq = 0.f;
          #pragma unroll
          for (int c = 0; c < 8; ++c) {
            v[c] = hb[lane + (c << 6)];
            sm += v[c]; sq += v[c] * v[c];
          }
          #pragma unroll
          for (int o = 32; o; o >>= 1) { sm += __shfl_xor(sm, o); sq += __shfl_xor(sq, o); }
          float m = sm * (1.f / 512.f);
          float rs = rsqrtf(sq * (1.f / 512.f) - m * m + 1e-3f);
          #pragma unroll
          for (int c = 0; c < 8; ++c) {
            int d = lane + (c << 6);
            float xx = (v[c] - m) * rs * gv[d] + bv[d];
            xx = xx * sigm(xx);
            u16 hi = f2b(xx);
            awr2(slotH, i, (hh << 9) + d, hi, f2b(xx - b2f(hi)));
          }
        }
      }
      __syncthreads();

      // ---- F: stats = h2 @ Ws (32 x 128, K=1024, 2-plane) + epilogue ----
      {
        f32x4 acc[2][2];
        #pragma unroll
        for (int a = 0; a < 2; ++a)
          #pragma unroll
          for (int bq = 0; bq < 2; ++bq) acc[a][bq] = f32x4{0.f, 0.f, 0.f, 0.f};
        gemm_pass<2, 32, 1000, 128>(slotH, p.WsT3, 8192,
                                    ldsA, ldsW, wave, lane, quad, l15, acc);
        #pragma unroll
        for (int mi = 0; mi < 2; ++mi)
          #pragma unroll
          for (int ni = 0; ni < 2; ++ni)
            #pragma unroll
            for (int rr = 0; rr < 4; ++rr) {
              int i = mi * 16 + quad * 4 + rr;
              int col = wave * 32 + ni * 16 + l15;
              if (i < Mk) {
                float v = acc[mi][ni][rr];
                int gi = row0 + i;
                int b = p.segb[gi], tt = p.segt0[gi] + k;
                float* orow = p.out + ((size_t)b * TT + tt) * 1216;
                if (col < 32) {
                  v += p.b_prior_stats[col];
                  orow[1120 + col] = v; orow[1152 + col] = v;
                } else if (col < 64) {
                  v = splus(v + p.b_prior_stats[col]) + 0.1f;
                  orow[1184 + col - 32] = v;
                } else if (col < 96) {
                  v += p.b_post_stats[col - 64];
                  orow[512 + col - 64] = v; orow[544 + col - 64] = v;
                  slotS[i * 32 + (col - 64)] = v;
                } else {
                  v = splus(v + p.b_post_stats[col - 64]) + 0.1f;
                  orow[576 + col - 96] = v;
                }
              }
            }
      }
      __syncthreads();
    }
  }
}

extern "C" void kernel_launch(void* const* d_in, const int* in_sizes, int n_in,
                              void* d_out, int out_size, void* d_ws, size_t ws_size,
                              hipStream_t stream) {
  P p;
  p.obs = (const float*)d_in[0];
  p.action = (const float*)d_in[1];
  p.is_first = (const int*)d_in[2];
  p.w_prior_in = (const float*)d_in[3];
  p.g_prior_in = (const float*)d_in[4];
  p.bb_prior_in = (const float*)d_in[5];
  p.w_gru = (const float*)d_in[6];
  p.g_gru = (const float*)d_in[7];
  p.bb_gru = (const float*)d_in[8];
  p.w_prior_out = (const float*)d_in[9];
  p.g_prior_out = (const float*)d_in[10];
  p.bb_prior_out = (const float*)d_in[11];
  p.w_prior_stats = (const float*)d_in[12];
  p.b_prior_stats = (const float*)d_in[13];
  p.w_post = (const float*)d_in[14];
  p.g_post = (const float*)d_in[15];
  p.bb_post = (const float*)d_in[16];
  p.w_post_stats = (const float*)d_in[17];
  p.b_post_stats = (const float*)d_in[18];
  p.initial_deter = (const float*)d_in[19];
  p.out = (float*)d_out;

  char* w = (char*)d_ws;
  auto alloc = [&](size_t bytes) -> char* {
    char* r = w; w += (bytes + 255) & ~(size_t)255; return r;
  };
  p.WgT3 = (u16*)alloc((size_t)192 * 16384 * 2);
  p.W2T3 = (u16*)alloc((size_t)68 * 16384 * 2);
  p.WsT3 = (u16*)alloc((size_t)32 * 8192 * 2);
  p.deter0 = (float*)alloc(512 * 4);
  p.init_mean = (float*)alloc(32 * 4);
  p.segb = (int*)alloc((size_t)65536 * 4);
  p.segt0 = (int*)alloc((size_t)65536 * 4);
  p.nact = (int*)alloc(257 * 4);
  size_t used = (size_t)(w - (char*)d_ws);
  size_t avail = ws_size > used ? ws_size - used : 0;
  // per-block slot: arow 135168 + h2 131072 + gates 196608 + hraw 131072
  //               + deter 65536 + stoch 4096 = 663552 B (+ alignment)
  size_t slot = 666112;
  long long nb = (long long)(avail / slot);
  if (nb > 256) nb = 256;
  if (nb < 1) nb = 1;
  p.NB = (int)nb;
  p.arow = (u16*)alloc((size_t)p.NB * 135168);
  p.h2 = (u16*)alloc((size_t)p.NB * 131072);
  p.gates = (float*)alloc((size_t)p.NB * 196608);
  p.hraw = (float*)alloc((size_t)p.NB * 131072);
  p.deter = (float*)alloc((size_t)p.NB * 65536);
  p.stoch = (float*)alloc((size_t)p.NB * 4096);

  k_weights<<<dim3(256), dim3(256), 0, stream>>>(p);
  k_init_state<<<dim3(1), dim3(256), 0, stream>>>(p);
  k_segments<<<dim3(1), dim3(256), 0, stream>>>(p);
  k_main<<<dim3(p.NB), dim3(BDIM), 0, stream>>>(p);
}